// Round 11
// baseline (115.438 us; speedup 1.0000x reference)
//
#include <hip/hip_runtime.h>
#include <hip/hip_bf16.h>
#include <cstdint>

typedef __attribute__((ext_vector_type(8))) __bf16 bf16x8;
typedef __attribute__((ext_vector_type(4))) float f32x4;
typedef unsigned short u16;
typedef unsigned int u32;

struct alignas(8) U16x4 { u16 x, y, z, w; };
struct alignas(8) U32x2 { u32 x, y; };

__device__ __forceinline__ u16 f2b(float x) {
    u32 u = __builtin_bit_cast(u32, x);
    u += 0x7fffu + ((u >> 16) & 1u);   // round-to-nearest-even
    return (u16)(u >> 16);
}
__device__ __forceinline__ u32 cvtpk(float lo, float hi) {
    u32 r;
    asm("v_cvt_pk_bf16_f32 %0, %1, %2" : "=v"(r) : "v"(lo), "v"(hi));
    return r;
}

// ---------------- kernel 1: f32 -> bf16 convert (hidden + concat weights) ----
__global__ __launch_bounds__(256) void cvt_kernel(
    const float* __restrict__ hs,
    const float* __restrict__ wq, const float* __restrict__ wk, const float* __restrict__ wv,
    u16* __restrict__ hsb, u16* __restrict__ wb)
{
    int i = blockIdx.x * 256 + threadIdx.x;       // float4 chunk index, exact grid
    const float4* src; u16* dst; int off;
    if (i < 1048576) { src = (const float4*)hs; dst = hsb; off = i; }
    else {
        int j = i - 1048576;                      // 3 * 262144 chunks
        int w = j >> 18;
        int o = j & 262143;
        src = (const float4*)(w == 0 ? wq : (w == 1 ? wk : wv));
        dst = wb + w * 1048576;
        off = o;
    }
    float4 v = src[off];
    U16x4 r; r.x = f2b(v.x); r.y = f2b(v.y); r.z = f2b(v.z); r.w = f2b(v.w);
    *(U16x4*)(dst + off * 4) = r;
}

// ---------------- kernel 2: QKV GEMM  C[4096,3072] = A[4096,1024] * W[3072,1024]^T
// BK=32 + double-buffered global_load_lds staging. Proven ~31 us (round 8/10).
__global__ __launch_bounds__(256, 3) void qkv_gemm(
    const u16* __restrict__ A, const u16* __restrict__ W,
    const float* __restrict__ bq, const float* __restrict__ bk, const float* __restrict__ bv,
    u16* __restrict__ Qo, u16* __restrict__ Ko, u16* __restrict__ Vt)
{
    __shared__ u16 As[2][128 * 32];   // 8 KB per buffer
    __shared__ u16 Bs[2][128 * 32];
    const int tid = threadIdx.x;
    const int lane = tid & 63, wid = tid >> 6;
    const int wr = (wid >> 1) * 64, wc = (wid & 1) * 64;  // wave sub-tile origin
    const int g = lane >> 4, c = lane & 15;

    int lin = blockIdx.y * 24 + blockIdx.x;
    int wg = (lin & 7) * 96 + (lin >> 3);
    const int bn = wg >> 5;      // 0..23
    const int bm = wg & 31;      // 0..31

    f32x4 acc[4][4] = {};

#define GSTAGE(bf, k0)                                                              \
    {                                                                               \
        _Pragma("unroll") for (int i = 0; i < 2; ++i) {                             \
            int chunk = i * 256 + tid;                                              \
            int row = chunk >> 2, col = (chunk & 3) * 8;                            \
            const u16* ga = A + (bm * 128 + row) * 1024 + (k0) + col;               \
            const u16* gb = W + (bn * 128 + row) * 1024 + (k0) + col;               \
            u16* la = &As[bf][0] + (i * 256 + wid * 64) * 8;                        \
            u16* lb = &Bs[bf][0] + (i * 256 + wid * 64) * 8;                        \
            __builtin_amdgcn_global_load_lds((const __attribute__((address_space(1))) u32*)ga, \
                                             (__attribute__((address_space(3))) u32*)la, 16, 0, 0); \
            __builtin_amdgcn_global_load_lds((const __attribute__((address_space(1))) u32*)gb, \
                                             (__attribute__((address_space(3))) u32*)lb, 16, 0, 0); \
        }                                                                           \
    }

    GSTAGE(0, 0);
    __syncthreads();

    int cur = 0;
    for (int t = 0; t < 32; ++t) {
        if (t < 31) GSTAGE(cur ^ 1, (t + 1) * 32);
        bf16x8 af[4], bf4[4];
        #pragma unroll
        for (int i = 0; i < 4; ++i)
            af[i] = *(const bf16x8*)(&As[cur][0] + (wr + i * 16 + c) * 32 + g * 8);
        #pragma unroll
        for (int j = 0; j < 4; ++j)
            bf4[j] = *(const bf16x8*)(&Bs[cur][0] + (wc + j * 16 + c) * 32 + g * 8);
        #pragma unroll
        for (int i = 0; i < 4; ++i)
            #pragma unroll
            for (int j = 0; j < 4; ++j)
                acc[i][j] = __builtin_amdgcn_mfma_f32_16x16x32_bf16(af[i], bf4[j], acc[i][j], 0, 0, 0);
        __syncthreads();
        cur ^= 1;
    }
#undef GSTAGE

    const int region = bn >> 3;                      // 0=Q 1=K 2=V
    const float* bias = region == 0 ? bq : (region == 1 ? bk : bv);
    #pragma unroll
    for (int i = 0; i < 4; ++i) {
        int m0 = bm * 128 + wr + i * 16 + g * 4;
        int b = m0 >> 10, s0 = m0 & 1023;
        #pragma unroll
        for (int j = 0; j < 4; ++j) {
            int n = (bn & 7) * 128 + wc + j * 16 + c;
            float bb = bias[n];
            int h = n >> 6, d = n & 63;
            int bh = b * 16 + h;
            if (region == 2) {
                U16x4 pk;
                pk.x = f2b(acc[i][j][0] + bb);
                pk.y = f2b(acc[i][j][1] + bb);
                pk.z = f2b(acc[i][j][2] + bb);
                pk.w = f2b(acc[i][j][3] + bb);
                *(U16x4*)(Vt + (bh * 64 + d) * 1024 + s0) = pk;
            } else if (region == 1) {
                #pragma unroll
                for (int r = 0; r < 4; ++r)
                    Ko[(bh * 1024 + s0 + r) * 64 + d] = f2b(acc[i][j][r] + bb);
            } else {
                #pragma unroll
                for (int r = 0; r < 4; ++r)
                    Qo[(bh * 1024 + s0 + r) * 64 + d] = f2b((acc[i][j][r] + bb) * 0.125f);
            }
        }
    }
}

// ---------------- kernel 3: fused attention, post-softmax multiplicative link mask
// Round-11 KV-SPLIT build: 1024 blocks x 512 threads (8 waves). Waves 0-3 (half 0)
// process keys 0..511, waves 4-7 (half 1) keys 512..1023, for the SAME 64 q-rows
// (wave qs = wid&3 owns 16 rows). Partial ctx/lsum merge once at the end via LDS
// (no online max -> partials just add). This doubles total waves (8192) ->
// 32 waves/CU = 8 waves/SIMD, halving exposed per-tile latency chains.
// LDS 32 KB -> 4 blocks/CU guaranteed; VGPR must stay <=64 (launch_bounds 512,8).
// K: global_load_lds double-buffered per half (source-preswizzled, rule #21).
// V: single-buffered, T14 reg-staged (load next tile to 1 reg/lane at tile top,
//    ds_write after the drain barrier, second lgkm-only barrier).
// P/V rows are 64 B -> 2-bit spread code u2=(c&3)^((c>>2)&3) XOR'd into chunk
// indices keeps reads bank-uniform.
__global__ __launch_bounds__(512, 8) void attn_kernel(
    const u16* __restrict__ Q, const u16* __restrict__ K, const u16* __restrict__ Vt,
    const float* __restrict__ amask, const float* __restrict__ link,
    float* __restrict__ out)
{
    __shared__ u16 Ks[2][2][32 * 64];   // [half][buf][k=32][d=64]  16 KB
    __shared__ u16 Vs[2][64 * 32];      // [half][d=64][k=32]        8 KB
    __shared__ u16 P[8][16 * 32];       // per-wave                  8 KB
    const int tid = threadIdx.x;
    const int lane = tid & 63, wid = tid >> 6;
    const int g = lane >> 4, c = lane & 15;
    const int c7 = c & 7;
    const int u2 = (c & 3) ^ ((c >> 2) & 3);   // bank spread code

    const int half = wid >> 2;          // kv half this wave computes
    const int qs   = wid & 3;           // q sub-tile (16 rows)

    // XCD swizzle: 1024 blocks; XCD x owns one b's half q-range across all heads.
    int hw = blockIdx.x;
    int logical = (hw & 7) * 128 + (hw >> 3);
    int b = logical >> 8;               // [0,4)
    int qt = (logical >> 4) & 15;       // [0,16) tiles of 64 q-rows
    int h = logical & 15;
    int bh = b * 16 + h;
    const int qbase = qt * 64 + qs * 16;

    const u16* Qh = Q + bh * 65536;
    const u16* Kh = K + bh * 65536;
    const u16* Vh = Vt + bh * 65536;
    const float* mk = amask + b * 1024;
    const float* lkq = link + (size_t)b * 1048576 + (size_t)(qbase + c) * 1024;

    bf16x8 qfx0 = *(const bf16x8*)(Qh + (qbase + c) * 64 + g * 8);
    bf16x8 qfx1 = *(const bf16x8*)(Qh + (qbase + c) * 64 + 32 + g * 8);

    // ---- staging roles (512 threads; thread stages for half sHalf) ----
    const int sHalf = tid >> 8;
    const int sIdx  = tid & 255;
    // K: 256 chunks = 32 rows x 8; source chunk-in-row preswizzled by row&7
    const int kRow = sIdx >> 3, kCir = sIdx & 7;
    const u16* KhS = Kh + (sHalf * 512 + kRow) * 64 + ((kCir ^ (kRow & 7)) * 8);
    u16* const kDst = &Ks[sHalf][0][0] + sIdx * 8;     // + buf*2048
    // V: 256 chunks = 64 d-rows x 4; dest slot swizzled by the row's spread code
    const int vRow = sIdx >> 2, vCir = sIdx & 3;
    const int vSlot = vCir ^ ((vRow & 3) ^ ((vRow >> 2) & 3));
    const u16* VhS = Vh + vRow * 1024 + sHalf * 512 + vCir * 8;
    u16* const vDst = &Vs[sHalf][0] + (vRow * 4 + vSlot) * 8;

#define KSTAGE(buf, kvt)                                                            \
    __builtin_amdgcn_global_load_lds(                                               \
        (const __attribute__((address_space(1))) u32*)(KhS + (kvt) * 64),           \
        (__attribute__((address_space(3))) u32*)(kDst + (buf) * 2048), 16, 0, 0);

    float lsum = 0.f;
    f32x4 ctx[4] = {};
    u16* const Pb = &P[wid][0];
    const u16* const KbBase = &Ks[half][0][0];
    const u16* const Vb = &Vs[half][0];

    // prologue: tile 0 of both halves
    {
        uint4 v0 = *(const uint4*)(VhS);
        KSTAGE(0, 0);
        __syncthreads();                 // vmcnt(0): K0 in LDS, v0 in regs
        *(uint4*)vDst = v0;
        __syncthreads();                 // V0 visible to all waves
    }

    for (int t = 0; t < 16; ++t) {
        uint4 vn = {};
        if (t < 15) {
            vn = *(const uint4*)(VhS + (t + 1) * 32);
            KSTAGE((t + 1) & 1, (t + 1) * 32);
        }
        const int kv = half * 512 + t * 32;
        const u16* Kb = KbBase + (t & 1) * 2048;

        // ---- QK^T + exp + link (2 x 16-key groups) ----
        #pragma unroll
        for (int kt = 0; kt < 2; ++kt) {
            f32x4 m4  = *(const f32x4*)(mk  + kv + kt * 16 + g * 4);
            f32x4 lk4 = *(const f32x4*)(lkq + kv + kt * 16 + g * 4);
            bf16x8 kf0 = *(const bf16x8*)(Kb + (kt * 16 + c) * 64 + ((g)     ^ c7) * 8);
            bf16x8 kf1 = *(const bf16x8*)(Kb + (kt * 16 + c) * 64 + ((4 + g) ^ c7) * 8);
            f32x4 sc = {};
            sc = __builtin_amdgcn_mfma_f32_16x16x32_bf16(kf0, qfx0, sc, 0, 0, 0);
            sc = __builtin_amdgcn_mfma_f32_16x16x32_bf16(kf1, qfx1, sc, 0, 0, 0);
            float e0 = __expf(sc[0] + m4[0]);
            float e1 = __expf(sc[1] + m4[1]);
            float e2 = __expf(sc[2] + m4[2]);
            float e3 = __expf(sc[3] + m4[3]);
            lsum += (e0 + e1) + (e2 + e3);
            U32x2 pw;
            pw.x = cvtpk(e0 * lk4[0], e1 * lk4[1]);
            pw.y = cvtpk(e2 * lk4[2], e3 * lk4[3]);
            *(U32x2*)(Pb + c * 32 + (((kt * 4 + g) ^ (u2 << 1)) * 4)) = pw;
        }
        // ---- PV: one k=32 MFMA per d-tile ----
        __builtin_amdgcn_s_setprio(1);
        bf16x8 pf = *(const bf16x8*)(Pb + c * 32 + (((g * 2) ^ (u2 << 1)) * 4));
        #pragma unroll
        for (int dt = 0; dt < 4; ++dt) {
            bf16x8 vf = *(const bf16x8*)(Vb + ((dt * 16 + c) * 4 + (g ^ u2)) * 8);
            ctx[dt] = __builtin_amdgcn_mfma_f32_16x16x32_bf16(pf, vf, ctx[dt], 0, 0, 0);
        }
        __builtin_amdgcn_s_setprio(0);
        __syncthreads();                 // V(t) reads done; K(t+1)+vn drained
        if (t < 15) *(uint4*)vDst = vn;
        __syncthreads();                 // V(t+1) visible (lgkm-only drain: cheap)
    }
#undef KSTAGE

    // ---- per-wave denominator over this wave's kv half ----
    lsum += __shfl_xor(lsum, 16, 64);
    lsum += __shfl_xor(lsum, 32, 64);

    // ---- cross-half merge via LDS (K/V/P regions are dead now) ----
    float* Mc = (float*)&Ks[0][0][0];    // 4096 floats: qs*1024 + q_local*64 + d
    float* Ml = (float*)&P[0][0];        // 64 floats: qs*16 + c
    if (half == 1) {
        #pragma unroll
        for (int dt = 0; dt < 4; ++dt)
            #pragma unroll
            for (int r = 0; r < 4; ++r)
                Mc[qs * 1024 + (g * 4 + r) * 64 + dt * 16 + c] = ctx[dt][r];
        if (g == 0) Ml[qs * 16 + c] = lsum;
    }
    __syncthreads();
    if (half == 0) {
        float lT = lsum + Ml[qs * 16 + c];
        #pragma unroll
        for (int r = 0; r < 4; ++r) {
            float inv = 1.0f / __shfl(lT, g * 4 + r, 16);
            int q = qbase + g * 4 + r;
            float* orow = out + (size_t)b * 1048576 + (size_t)q * 1024 + h * 64;
            #pragma unroll
            for (int dt = 0; dt < 4; ++dt)
                orow[dt * 16 + c] =
                    (ctx[dt][r] + Mc[qs * 1024 + (g * 4 + r) * 64 + dt * 16 + c]) * inv;
        }
    }
}

extern "C" void kernel_launch(void* const* d_in, const int* in_sizes, int n_in,
                              void* d_out, int out_size, void* d_ws, size_t ws_size,
                              hipStream_t stream)
{
    (void)in_sizes; (void)n_in; (void)out_size; (void)ws_size;
    const float* hs    = (const float*)d_in[0];
    const float* amask = (const float*)d_in[1];
    const float* link  = (const float*)d_in[2];
    const float* Wq    = (const float*)d_in[3];
    const float* bq    = (const float*)d_in[4];
    const float* Wk    = (const float*)d_in[5];
    const float* bk    = (const float*)d_in[6];
    const float* Wv    = (const float*)d_in[7];
    const float* bv    = (const float*)d_in[8];
    float* out = (float*)d_out;

    char* ws = (char*)d_ws;
    u16* hsb = (u16*)ws;                   // 8 MiB  [4096][1024] bf16
    u16* wb  = (u16*)(ws + (8u  << 20));   // 6 MiB  [3072][1024] bf16 (Wq|Wk|Wv)
    u16* Qb  = (u16*)(ws + (14u << 20));   // 8 MiB  [B,H,S,64]  (pre-scaled by 0.125)
    u16* Kb  = (u16*)(ws + (22u << 20));   // 8 MiB  [B,H,S,64]
    u16* Vtb = (u16*)(ws + (30u << 20));   // 8 MiB  [B,H,64,S]

    cvt_kernel<<<7168, 256, 0, stream>>>(hs, Wq, Wk, Wv, hsb, wb);
    qkv_gemm<<<dim3(24, 32), 256, 0, stream>>>(hsb, wb, bq, bk, bv, Qb, Kb, Vtb);
    attn_kernel<<<1024, 512, 0, stream>>>(Qb, Kb, Vtb, amask, link, out);
}

// Round 12
// 97.416 us; speedup vs baseline: 1.1850x; 1.1850x over previous
//
#include <hip/hip_runtime.h>
#include <hip/hip_bf16.h>
#include <cstdint>

typedef __attribute__((ext_vector_type(8))) __bf16 bf16x8;
typedef __attribute__((ext_vector_type(4))) float f32x4;
typedef unsigned short u16;
typedef unsigned int u32;

struct alignas(8) U16x4 { u16 x, y, z, w; };
struct alignas(8) U32x2 { u32 x, y; };

__device__ __forceinline__ u16 f2b(float x) {
    u32 u = __builtin_bit_cast(u32, x);
    u += 0x7fffu + ((u >> 16) & 1u);   // round-to-nearest-even
    return (u16)(u >> 16);
}
__device__ __forceinline__ u32 cvtpk(float lo, float hi) {
    u32 r;
    asm("v_cvt_pk_bf16_f32 %0, %1, %2" : "=v"(r) : "v"(lo), "v"(hi));
    return r;
}

// ---------------- kernel 1: f32 -> bf16 convert (hidden + concat weights) ----
__global__ __launch_bounds__(256) void cvt_kernel(
    const float* __restrict__ hs,
    const float* __restrict__ wq, const float* __restrict__ wk, const float* __restrict__ wv,
    u16* __restrict__ hsb, u16* __restrict__ wb)
{
    int i = blockIdx.x * 256 + threadIdx.x;       // float4 chunk index, exact grid
    const float4* src; u16* dst; int off;
    if (i < 1048576) { src = (const float4*)hs; dst = hsb; off = i; }
    else {
        int j = i - 1048576;                      // 3 * 262144 chunks
        int w = j >> 18;
        int o = j & 262143;
        src = (const float4*)(w == 0 ? wq : (w == 1 ? wk : wv));
        dst = wb + w * 1048576;
        off = o;
    }
    float4 v = src[off];
    U16x4 r; r.x = f2b(v.x); r.y = f2b(v.y); r.z = f2b(v.z); r.w = f2b(v.w);
    *(U16x4*)(dst + off * 4) = r;
}

// ---------------- kernel 2: QKV GEMM  C[4096,3072] = A[4096,1024] * W[3072,1024]^T
// BK=32 double-buffered global_load_lds. ROUND-12 REORDER: the loop is now
// {barrier; issue STAGE(t+1); compute(t)} instead of {issue; compute; barrier}.
// __syncthreads' implicit s_waitcnt vmcnt(0) previously drained a stage issued
// only ~200 cy earlier (exposing ~400-700 cy of L2 latency EVERY iter); now it
// drains a stage issued a full compute phase ago (already landed), and the new
// stage flows under compute. Hazards: buf[cur^1] reads all precede the barrier;
// buf[cur]'s stage is drained by it.
__global__ __launch_bounds__(256, 3) void qkv_gemm(
    const u16* __restrict__ A, const u16* __restrict__ W,
    const float* __restrict__ bq, const float* __restrict__ bk, const float* __restrict__ bv,
    u16* __restrict__ Qo, u16* __restrict__ Ko, u16* __restrict__ Vt)
{
    __shared__ u16 As[2][128 * 32];   // 8 KB per buffer
    __shared__ u16 Bs[2][128 * 32];
    const int tid = threadIdx.x;
    const int lane = tid & 63, wid = tid >> 6;
    const int wr = (wid >> 1) * 64, wc = (wid & 1) * 64;  // wave sub-tile origin
    const int g = lane >> 4, c = lane & 15;

    int lin = blockIdx.y * 24 + blockIdx.x;
    int wg = (lin & 7) * 96 + (lin >> 3);
    const int bn = wg >> 5;      // 0..23
    const int bm = wg & 31;      // 0..31

    f32x4 acc[4][4] = {};

#define GSTAGE(bf, k0)                                                              \
    {                                                                               \
        _Pragma("unroll") for (int i = 0; i < 2; ++i) {                             \
            int chunk = i * 256 + tid;                                              \
            int row = chunk >> 2, col = (chunk & 3) * 8;                            \
            const u16* ga = A + (bm * 128 + row) * 1024 + (k0) + col;               \
            const u16* gb = W + (bn * 128 + row) * 1024 + (k0) + col;               \
            u16* la = &As[bf][0] + (i * 256 + wid * 64) * 8;                        \
            u16* lb = &Bs[bf][0] + (i * 256 + wid * 64) * 8;                        \
            __builtin_amdgcn_global_load_lds((const __attribute__((address_space(1))) u32*)ga, \
                                             (__attribute__((address_space(3))) u32*)la, 16, 0, 0); \
            __builtin_amdgcn_global_load_lds((const __attribute__((address_space(1))) u32*)gb, \
                                             (__attribute__((address_space(3))) u32*)lb, 16, 0, 0); \
        }                                                                           \
    }

    GSTAGE(0, 0);

    int cur = 0;
    for (int t = 0; t < 32; ++t) {
        __syncthreads();              // stage(t) drained (issued one phase ago);
                                      // prev compute done -> buf[cur^1] free
        if (t < 31) GSTAGE(cur ^ 1, (t + 1) * 32);   // overlaps compute below
        bf16x8 af[4], bf4[4];
        #pragma unroll
        for (int i = 0; i < 4; ++i)
            af[i] = *(const bf16x8*)(&As[cur][0] + (wr + i * 16 + c) * 32 + g * 8);
        #pragma unroll
        for (int j = 0; j < 4; ++j)
            bf4[j] = *(const bf16x8*)(&Bs[cur][0] + (wc + j * 16 + c) * 32 + g * 8);
        #pragma unroll
        for (int i = 0; i < 4; ++i)
            #pragma unroll
            for (int j = 0; j < 4; ++j)
                acc[i][j] = __builtin_amdgcn_mfma_f32_16x16x32_bf16(af[i], bf4[j], acc[i][j], 0, 0, 0);
        cur ^= 1;
    }
#undef GSTAGE

    const int region = bn >> 3;                      // 0=Q 1=K 2=V
    const float* bias = region == 0 ? bq : (region == 1 ? bk : bv);
    #pragma unroll
    for (int i = 0; i < 4; ++i) {
        int m0 = bm * 128 + wr + i * 16 + g * 4;
        int b = m0 >> 10, s0 = m0 & 1023;
        #pragma unroll
        for (int j = 0; j < 4; ++j) {
            int n = (bn & 7) * 128 + wc + j * 16 + c;
            float bb = bias[n];
            int h = n >> 6, d = n & 63;
            int bh = b * 16 + h;
            if (region == 2) {
                U16x4 pk;
                pk.x = f2b(acc[i][j][0] + bb);
                pk.y = f2b(acc[i][j][1] + bb);
                pk.z = f2b(acc[i][j][2] + bb);
                pk.w = f2b(acc[i][j][3] + bb);
                *(U16x4*)(Vt + (bh * 64 + d) * 1024 + s0) = pk;
            } else if (region == 1) {
                #pragma unroll
                for (int r = 0; r < 4; ++r)
                    Ko[(bh * 1024 + s0 + r) * 64 + d] = f2b(acc[i][j][r] + bb);
            } else {
                #pragma unroll
                for (int r = 0; r < 4; ++r)
                    Qo[(bh * 1024 + s0 + r) * 64 + d] = f2b((acc[i][j][r] + bb) * 0.125f);
            }
        }
    }
}

// ---------------- kernel 3: fused attention, post-softmax multiplicative link mask
// Round-10 structure (best measured: K+V LDS-staged dbuf, P per-wave stride-64
// XOR-swizzled, 40 KB LDS, 1024 blocks x 4 waves x 16 q-rows, 4 blocks/CU) with
// the ROUND-12 REORDER: {barrier; issue STAGE(t+1); compute(t)} so the barrier's
// vmcnt(0) drains a one-phase-old stage (free) instead of the just-issued one
// (which exposed the full L2 latency every tile).
// No online max: scores are O(10), exp() safe in f32; denom reduced at the end.
__global__ __launch_bounds__(256, 4) void attn_kernel(
    const u16* __restrict__ Q, const u16* __restrict__ K, const u16* __restrict__ Vt,
    const float* __restrict__ amask, const float* __restrict__ link,
    float* __restrict__ out)
{
    __shared__ u16 Ks[2][64 * 64];     // 8 KB per buffer
    __shared__ u16 Vs[2][64 * 64];     // 8 KB per buffer
    __shared__ u16 P[4][16 * 64];      // per-wave [q=16][k=64], XOR-swizzled banks
    const int tid = threadIdx.x;
    const int lane = tid & 63, wid = tid >> 6;
    const int g = lane >> 4, c = lane & 15;
    const int c7 = c & 7;

    // XCD swizzle: 1024 blocks; XCD x owns logical x*128..x*128+127 = half a
    // batch's q-range (512 q-rows, 2 MB link slice) across all 16 heads.
    int hw = blockIdx.x;
    int logical = (hw & 7) * 128 + (hw >> 3);
    int b = logical >> 8;              // [0,4)
    int qt = (logical >> 4) & 15;      // [0,16) tiles of 64 q-rows
    int h = logical & 15;
    int bh = b * 16 + h;
    const int qbase = qt * 64 + wid * 16;

    const u16* Qh = Q + bh * 65536;
    const u16* Kh = K + bh * 65536;
    const u16* Vh = Vt + bh * 65536;
    const float* mk = amask + b * 1024;
    const float* lkq = link + (size_t)b * 1048576 + (size_t)(qbase + c) * 1024;

    bf16x8 qfx0 = *(const bf16x8*)(Qh + (qbase + c) * 64 + g * 8);
    bf16x8 qfx1 = *(const bf16x8*)(Qh + (qbase + c) * 64 + 32 + g * 8);

    float lsum = 0.f;
    f32x4 ctx[4] = {};
    u16* const Pb = &P[wid][0];

    // stage K+V kv-tile into buffer bf: 512+512 chunks of 16B. Source chunk-in-row
    // XOR-swizzled so LDS stays linear (rule #21); rows are 128 B -> needs it.
#define ASTAGE(bf, kv)                                                              \
    {                                                                               \
        _Pragma("unroll") for (int i = 0; i < 2; ++i) {                             \
            int chunk = i * 256 + tid;                                              \
            int row = chunk >> 3;                                                   \
            int scir = (chunk & 7) ^ (row & 7);                                     \
            const u16* gk = Kh + ((kv) + row) * 64 + scir * 8;                      \
            const u16* gv = Vh + row * 1024 + (kv) + scir * 8;                      \
            u16* lk = &Ks[bf][0] + (i * 256 + wid * 64) * 8;                        \
            u16* lv = &Vs[bf][0] + (i * 256 + wid * 64) * 8;                        \
            __builtin_amdgcn_global_load_lds((const __attribute__((address_space(1))) u32*)gk, \
                                             (__attribute__((address_space(3))) u32*)lk, 16, 0, 0); \
            __builtin_amdgcn_global_load_lds((const __attribute__((address_space(1))) u32*)gv, \
                                             (__attribute__((address_space(3))) u32*)lv, 16, 0, 0); \
        }                                                                           \
    }

    ASTAGE(0, 0);

    int cur = 0;
    for (int t = 0; t < 16; ++t) {
        __syncthreads();               // stage(t) drained (issued one phase ago);
                                       // prev compute done -> buf[cur^1] free
        if (t < 15) ASTAGE(cur ^ 1, (t + 1) * 64);  // overlaps compute below
        const int kv = t * 64;
        const u16* Kb = &Ks[cur][0];
        const u16* Vb = &Vs[cur][0];

        // hoist this tile's mask + link loads (independent of MFMA chain)
        f32x4 m4[4], lk4[4];
        #pragma unroll
        for (int kt = 0; kt < 4; ++kt) {
            m4[kt]  = *(const f32x4*)(mk  + kv + kt * 16 + g * 4);
            lk4[kt] = *(const f32x4*)(lkq + kv + kt * 16 + g * 4);
        }

        // ---- QK^T + exp + link, one 16-key group at a time ----
        #pragma unroll
        for (int kt = 0; kt < 4; ++kt) {
            bf16x8 kf0 = *(const bf16x8*)(Kb + (kt * 16 + c) * 64 + ((g)     ^ c7) * 8);
            bf16x8 kf1 = *(const bf16x8*)(Kb + (kt * 16 + c) * 64 + ((4 + g) ^ c7) * 8);
            f32x4 sc = {};
            sc = __builtin_amdgcn_mfma_f32_16x16x32_bf16(kf0, qfx0, sc, 0, 0, 0);
            sc = __builtin_amdgcn_mfma_f32_16x16x32_bf16(kf1, qfx1, sc, 0, 0, 0);
            float e0 = __expf(sc[0] + m4[kt][0]);
            float e1 = __expf(sc[1] + m4[kt][1]);
            float e2 = __expf(sc[2] + m4[kt][2]);
            float e3 = __expf(sc[3] + m4[kt][3]);
            lsum += (e0 + e1) + (e2 + e3);
            U32x2 pw;
            pw.x = cvtpk(e0 * lk4[kt][0], e1 * lk4[kt][1]);
            pw.y = cvtpk(e2 * lk4[kt][2], e3 * lk4[kt][3]);
            // P write: row c, 8B-chunk (kt*4+g) ^ ((c&7)<<1)  [bank-uniform]
            *(U32x2*)(Pb + c * 64 + (((kt * 4 + g) ^ (c7 << 1)) * 4)) = pw;
        }
        // ---- PV: P from per-wave LDS (in-order DS pipe), V from staged tile ----
        __builtin_amdgcn_s_setprio(1);
        #pragma unroll
        for (int kk = 0; kk < 2; ++kk) {
            // P read: row c, 16B pair starting at chunk (kk*8+g*2) ^ ((c&7)<<1)
            bf16x8 pf = *(const bf16x8*)(Pb + c * 64 + (((kk * 8 + g * 2) ^ (c7 << 1)) * 4));
            #pragma unroll
            for (int dt = 0; dt < 4; ++dt) {
                bf16x8 vf = *(const bf16x8*)(Vb + (dt * 16 + c) * 64 + ((kk * 4 + g) ^ c7) * 8);
                ctx[dt] = __builtin_amdgcn_mfma_f32_16x16x32_bf16(pf, vf, ctx[dt], 0, 0, 0);
            }
        }
        __builtin_amdgcn_s_setprio(0);
        cur ^= 1;
    }
#undef ASTAGE

    lsum += __shfl_xor(lsum, 16, 64);
    lsum += __shfl_xor(lsum, 32, 64);

    #pragma unroll
    for (int r = 0; r < 4; ++r) {
        float inv = 1.0f / __shfl(lsum, g * 4 + r, 16);
        int q = qbase + g * 4 + r;
        float* orow = out + (size_t)b * 1048576 + (size_t)q * 1024 + h * 64;
        #pragma unroll
        for (int dt = 0; dt < 4; ++dt)
            orow[dt * 16 + c] = ctx[dt][r] * inv;
    }
}

extern "C" void kernel_launch(void* const* d_in, const int* in_sizes, int n_in,
                              void* d_out, int out_size, void* d_ws, size_t ws_size,
                              hipStream_t stream)
{
    (void)in_sizes; (void)n_in; (void)out_size; (void)ws_size;
    const float* hs    = (const float*)d_in[0];
    const float* amask = (const float*)d_in[1];
    const float* link  = (const float*)d_in[2];
    const float* Wq    = (const float*)d_in[3];
    const float* bq    = (const float*)d_in[4];
    const float* Wk    = (const float*)d_in[5];
    const float* bk    = (const float*)d_in[6];
    const float* Wv    = (const float*)d_in[7];
    const float* bv    = (const float*)d_in[8];
    float* out = (float*)d_out;

    char* ws = (char*)d_ws;
    u16* hsb = (u16*)ws;                   // 8 MiB  [4096][1024] bf16
    u16* wb  = (u16*)(ws + (8u  << 20));   // 6 MiB  [3072][1024] bf16 (Wq|Wk|Wv)
    u16* Qb  = (u16*)(ws + (14u << 20));   // 8 MiB  [B,H,S,64]  (pre-scaled by 0.125)
    u16* Kb  = (u16*)(ws + (22u << 20));   // 8 MiB  [B,H,S,64]
    u16* Vtb = (u16*)(ws + (30u << 20));   // 8 MiB  [B,H,64,S]

    cvt_kernel<<<7168, 256, 0, stream>>>(hs, Wq, Wk, Wv, hsb, wb);
    qkv_gemm<<<dim3(24, 32), 256, 0, stream>>>(hsb, wb, bq, bk, bv, Qb, Kb, Vtb);
    attn_kernel<<<1024, 256, 0, stream>>>(Qb, Kb, Vtb, amask, link, out);
}